// Round 1
// baseline (1070.526 us; speedup 1.0000x reference)
//
#include <hip/hip_runtime.h>
#include <cstddef>

namespace {

constexpr int   kN     = 512;
constexpr int   kB     = 64;
constexpr float kAlpha = 0.8f;
constexpr float kGamma = 0.01f;
constexpr float kInvG  = 100.0f;   // 1/gamma
constexpr float kG     = 0.05f;
constexpr float kBig   = 1e8f;

// Diagonal-packed R storage: diag k (k = i+j-2, i,j in [1,N]) starts at P(k),
// cell (i,j) stored at P(k) + (i - i_min(k)). Total N*N floats per batch.
__device__ __forceinline__ int diag_imin(int k) {
    return (k < kN) ? 1 : (k + 2 - kN);
}
__device__ __forceinline__ int diag_off(int k) {
    return (k < kN) ? (k * (k + 1) / 2)
                    : (kN * (kN + 1) / 2 + (kN - 1) * kN / 2
                       - (2 * kN - k - 1) * (2 * kN - k) / 2);
}

__global__ __launch_bounds__(512)
void dilate_fwd_bwd(const float* __restrict__ input,
                    const float* __restrict__ target,
                    float* __restrict__ Rg,          // per-launch slots, kN*kN each
                    float* __restrict__ partials,    // [kB]
                    int b0) {
    __shared__ float sx[kN];          // input row  (x, index j-1)
    __shared__ float st_[kN];         // target row (t, index i-1)
    __shared__ float sw[kN];          // exp time weights (index i-1)
    __shared__ float rb[3][kN + 1];   // rotating R diagonals, indexed by row i (0..N)
    __shared__ float ebuf[3][kN + 1]; // rotating E diagonals
    __shared__ float red[512];
    __shared__ float s_rnn;

    const int tid = threadIdx.x;
    const int b   = b0 + blockIdx.x;
    const int i   = tid + 1;          // row index, 1..N
    float* __restrict__ Rb = Rg + (size_t)blockIdx.x * (size_t)(kN * kN);

    // ---- load series + compute normalized exp weights -------------------
    sx[tid]  = input[(size_t)b * kN + tid];
    st_[tid] = target[(size_t)b * kN + tid];
    const float ew = expf(kG * (float)tid);
    red[tid] = ew;
    __syncthreads();
    #pragma unroll
    for (int s = 256; s > 0; s >>= 1) {
        if (tid < s) red[tid] += red[tid + s];
        __syncthreads();
    }
    sw[tid] = ew * ((float)kN / red[0]);

    // ---- forward soft-DTW over anti-diagonals ----------------------------
    rb[0][i] = kBig; rb[1][i] = kBig; rb[2][i] = kBig;
    if (tid == 0) { rb[0][0] = 0.0f; rb[1][0] = kBig; rb[2][0] = kBig; }
    __syncthreads();

    const float ti = st_[tid];   // t[i-1]
    const float wi = sw[tid];    // w[i-1]

    int ir2 = 0, ir1 = 1, irc = 2;   // diag k-2, k-1, k
    for (int k = 0; k <= 2 * kN - 2; ++k) {
        const int j = k + 2 - i;
        const bool valid = (j >= 1) && (j <= kN);
        float val = kBig;
        if (valid) {
            const float a  = rb[ir2][i - 1];   // R[i-1][j-1]
            const float bb = rb[ir1][i - 1];   // R[i-1][j]
            const float c  = rb[ir1][i];       // R[i][j-1]
            const float dx = ti - sx[j - 1];
            const float d  = wi * dx * dx;
            const float m  = fminf(a, fminf(bb, c));
            const float ss = expf((m - a) * kInvG) + expf((m - bb) * kInvG)
                           + expf((m - c) * kInvG);
            val = d + m - kGamma * logf(ss);
            Rb[diag_off(k) + (i - diag_imin(k))] = val;     // coalesced per diag
            if (k == 2 * kN - 2) s_rnn = val;               // R[N,N], thread i==N
        }
        rb[irc][i] = val;
        if (tid == 0) rb[irc][0] = kBig;
        __syncthreads();
        const int t0 = ir2; ir2 = ir1; ir1 = irc; irc = t0;
    }

    // ---- backward: E = dR[N,N]/dD over reverse anti-diagonals ------------
    ebuf[0][i] = 0.0f; ebuf[1][i] = 0.0f; ebuf[2][i] = 0.0f;
    rb[0][i] = kBig; rb[1][i] = kBig; rb[2][i] = kBig;
    if (tid == 0) {
        ebuf[0][0] = 0.0f; ebuf[1][0] = 0.0f; ebuf[2][0] = 0.0f;
        rb[0][0] = kBig; rb[1][0] = kBig; rb[2][0] = kBig;
    }
    __syncthreads();

    int cur = 0, p1 = 1, p2 = 2;     // diag k, k+1, k+2
    float acc = 0.0f;
    for (int k = 2 * kN - 2; k >= 0; --k) {
        const int j = k + 2 - i;
        const bool valid = (j >= 1) && (j <= kN);
        float Ev = 0.0f, Rv = kBig;
        if (valid) {
            Rv = Rb[diag_off(k) + (i - diag_imin(k))];
            if (k == 2 * kN - 2) {
                Ev = 1.0f;            // E[N][N]
            } else {
                float s = 0.0f;
                if (i + 1 <= kN) {    // vertical successor (i+1, j), diag k+1
                    const float dd = st_[i] - sx[j - 1];
                    s += ebuf[p1][i + 1]
                       * expf((rb[p1][i + 1] - sw[i] * dd * dd - Rv) * kInvG);
                }
                if (j + 1 <= kN) {    // horizontal successor (i, j+1), diag k+1
                    const float dd = ti - sx[j];
                    s += ebuf[p1][i]
                       * expf((rb[p1][i] - wi * dd * dd - Rv) * kInvG);
                }
                if (i + 1 <= kN && j + 1 <= kN) {  // diagonal successor, diag k+2
                    const float dd = st_[i] - sx[j];
                    s += ebuf[p2][i + 1]
                       * expf((rb[p2][i + 1] - sw[i] * dd * dd - Rv) * kInvG);
                }
                Ev = s;
            }
            const float dij = (float)(i - j);
            acc += Ev * dij * dij;
        }
        ebuf[cur][i] = Ev;
        rb[cur][i]   = Rv;
        __syncthreads();
        const int t0 = p2; p2 = p1; p1 = cur; cur = t0;
    }

    // ---- block reduce temporal term, write per-batch partial --------------
    red[tid] = acc;
    __syncthreads();
    #pragma unroll
    for (int s = 256; s > 0; s >>= 1) {
        if (tid < s) red[tid] += red[tid + s];
        __syncthreads();
    }
    if (tid == 0) {
        const float temporal = red[0] * (1.0f / ((float)kN * (float)kN));
        partials[b] = (kAlpha * s_rnn + (1.0f - kAlpha) * temporal)
                    * (1.0f / (float)kB);
    }
}

__global__ void dilate_finalize(const float* __restrict__ partials,
                                float* __restrict__ out) {
    float v = partials[threadIdx.x];   // 64 threads = one wave
    #pragma unroll
    for (int off = 32; off > 0; off >>= 1) v += __shfl_down(v, off);
    if (threadIdx.x == 0) out[0] = v;
}

} // namespace

extern "C" void kernel_launch(void* const* d_in, const int* in_sizes, int n_in,
                              void* d_out, int out_size, void* d_ws, size_t ws_size,
                              hipStream_t stream) {
    (void)in_sizes; (void)n_in; (void)out_size;
    const float* input  = (const float*)d_in[0];
    const float* target = (const float*)d_in[1];
    float* out      = (float*)d_out;
    float* partials = (float*)d_ws;                       // kB floats
    float* Rbase    = (float*)((char*)d_ws + 1024);       // R slots

    const size_t per_batch = (size_t)kN * kN * sizeof(float);  // 1 MiB
    const size_t avail = (ws_size > 1024) ? (ws_size - 1024) : 0;
    int cap = (int)(avail / per_batch);
    if (cap > kB) cap = kB;
    if (cap < 1)  cap = 1;   // assume ws holds at least one batch's R

    for (int b0 = 0; b0 < kB; b0 += cap) {
        const int nb = (kB - b0 < cap) ? (kB - b0) : cap;
        hipLaunchKernelGGL(dilate_fwd_bwd, dim3(nb), dim3(512), 0, stream,
                           input, target, Rbase, partials, b0);
    }
    hipLaunchKernelGGL(dilate_finalize, dim3(1), dim3(64), 0, stream,
                       partials, out);
}